// Round 2
// baseline (196.527 us; speedup 1.0000x reference)
//
#include <hip/hip_runtime.h>

// ---------------------------------------------------------------------------
// WelkirSelfAttention: B=4 S=1024 D=768 H=12 DH=64, relative_key_query bias +
// flow-type scalar bias. Pipeline:
//   k_prep : cast hidden/W{q,k,v}/dist_emb -> bf16 (dist padded to 2048 rows)
//   k_flow : flow[b,i,j] = ce[cfg]+de[dfg]+re[rdg] (idx0 -> 0) -> bf16 [B,S,S]
//   k_qkv  : GEMM [4096 x 2304 x 768] bf16 MFMA -> Q,K,V bf16 [B,H,S,64]
//   k_vt   : V -> V^T  [B,H,64,S]
//   k_attn : fused flash attention, sheared QD/KD panels, 57.8KB static LDS
// ---------------------------------------------------------------------------

typedef __attribute__((ext_vector_type(4))) float f32x4;
typedef __attribute__((ext_vector_type(8))) short s16x8;

#define MFMA_BF16 __builtin_amdgcn_mfma_f32_16x16x32_bf16

__device__ __forceinline__ unsigned short f2bf(float x) {
  unsigned u = __builtin_bit_cast(unsigned, x);
  u += 0x7fffu + ((u >> 16) & 1u);
  return (unsigned short)(u >> 16);
}
__device__ __forceinline__ float bf2f(unsigned short h) {
  unsigned u = ((unsigned)h) << 16;
  return __builtin_bit_cast(float, u);
}
__device__ __forceinline__ void gl_lds16(const void* g, void* l) {
  __builtin_amdgcn_global_load_lds(
      (const __attribute__((address_space(1))) unsigned int*)g,
      (__attribute__((address_space(3))) unsigned int*)l, 16, 0, 0);
}

// ---------------------------------------------------------------------------
// k_prep: bf16 casts. ranges: [0,3145728) hs ; [.,+1769472) packed W ; dist.
// ---------------------------------------------------------------------------
__global__ __launch_bounds__(256) void k_prep(
    const float* __restrict__ hs, const float* __restrict__ wq,
    const float* __restrict__ wk, const float* __restrict__ wv,
    const float* __restrict__ de, unsigned short* __restrict__ hsb,
    unsigned short* __restrict__ wb, unsigned short* __restrict__ db) {
  const long HSN = 3145728, WN = 1769472;
  long e = ((long)blockIdx.x * 256 + threadIdx.x) * 4;
  if (e < HSN) {
    float4 v = *(const float4*)(hs + e);
    *(ushort4*)(hsb + e) = make_ushort4(f2bf(v.x), f2bf(v.y), f2bf(v.z), f2bf(v.w));
  } else if (e < HSN + WN) {
    long ew = e - HSN;
    const float* src = (ew >= 1179648) ? wv : ((ew >= 589824) ? wk : wq);
    long off = (ew >= 1179648) ? (ew - 1179648) : ((ew >= 589824) ? (ew - 589824) : ew);
    float4 v = *(const float4*)(src + off);
    *(ushort4*)(wb + ew) = make_ushort4(f2bf(v.x), f2bf(v.y), f2bf(v.z), f2bf(v.w));
  } else {
    long ed = e - HSN - WN;  // [0, 131072)
    ushort4 ov;
    if (ed < 131008) {  // 2047*64 valid rows, rest zero pad
      float4 v = *(const float4*)(de + ed);
      ov = make_ushort4(f2bf(v.x), f2bf(v.y), f2bf(v.z), f2bf(v.w));
    } else {
      ov = make_ushort4(0, 0, 0, 0);
    }
    *(ushort4*)(db + ed) = ov;
  }
}

// ---------------------------------------------------------------------------
// k_flow: combined scalar flow bias, row 0 of each embedding forced to zero.
// ---------------------------------------------------------------------------
__global__ __launch_bounds__(256) void k_flow(
    const int* __restrict__ cm, const int* __restrict__ dm,
    const int* __restrict__ rm, const float* __restrict__ ce,
    const float* __restrict__ dfe, const float* __restrict__ rfe,
    unsigned short* __restrict__ fl) {
  long e = ((long)blockIdx.x * 256 + threadIdx.x) * 4;
  int4 c = *(const int4*)(cm + e);
  int4 d = *(const int4*)(dm + e);
  int4 r = *(const int4*)(rm + e);
  ushort4 ov;
  ov.x = f2bf((c.x ? ce[c.x] : 0.f) + (d.x ? dfe[d.x] : 0.f) + (r.x ? rfe[r.x] : 0.f));
  ov.y = f2bf((c.y ? ce[c.y] : 0.f) + (d.y ? dfe[d.y] : 0.f) + (r.y ? rfe[r.y] : 0.f));
  ov.z = f2bf((c.z ? ce[c.z] : 0.f) + (d.z ? dfe[d.z] : 0.f) + (r.z ? rfe[r.z] : 0.f));
  ov.w = f2bf((c.w ? ce[c.w] : 0.f) + (d.w ? dfe[d.w] : 0.f) + (r.w ? rfe[r.w] : 0.f));
  *(ushort4*)(fl + e) = ov;
}

// ---------------------------------------------------------------------------
// k_qkv: C[token,m] = hs_bf16 @ W'[m,:]^T + bias; scatter to [t][B,H,S,64] bf16
// 128x128 tile, BK=32, 4 waves, global_load_lds w16, XOR((row>>1)&3) swizzle.
// Single shared array: A-tile at +0 (8192B), B-tile at +8192.
// ---------------------------------------------------------------------------
__global__ __launch_bounds__(256) void k_qkv(
    const unsigned short* __restrict__ A, const unsigned short* __restrict__ W,
    const float* __restrict__ bq, const float* __restrict__ bk,
    const float* __restrict__ bv, unsigned short* __restrict__ Qp,
    unsigned short* __restrict__ Kp, unsigned short* __restrict__ Vp) {
  __shared__ __align__(16) char smq[16384];
  char* sa = smq;
  char* sb = smq + 8192;
  const int tid = threadIdx.x, w = tid >> 6, lane = tid & 63;
  const int g = lane >> 4, l15 = lane & 15;
  const int n0 = blockIdx.x * 128, m0 = blockIdx.y * 128;
  const int wm = w >> 1, wn = w & 1;
  f32x4 acc[4][4] = {};
  for (int k0 = 0; k0 < 768; k0 += 32) {
#pragma unroll
    for (int it = 0; it < 2; ++it) {
      const int c = (w << 7) + (it << 6) + lane;
      const int row = c >> 2, sl = c & 3;
      const int so = ((sl ^ ((row >> 1) & 3)) << 3);
      char* dst = smq + ((w << 7) + (it << 6)) * 16;
      gl_lds16(A + (long)(m0 + row) * 768 + k0 + so, dst);
      gl_lds16(W + (long)(n0 + row) * 768 + k0 + so, dst + 8192);
    }
    __syncthreads();
    s16x8 af[4], bf[4];
#pragma unroll
    for (int mi = 0; mi < 4; ++mi) {
      const int row = wm * 64 + mi * 16 + l15;
      af[mi] = *(const s16x8*)(sa + row * 64 + ((g ^ ((row >> 1) & 3)) << 4));
    }
#pragma unroll
    for (int ni = 0; ni < 4; ++ni) {
      const int row = wn * 64 + ni * 16 + l15;
      bf[ni] = *(const s16x8*)(sb + row * 64 + ((g ^ ((row >> 1) & 3)) << 4));
    }
#pragma unroll
    for (int mi = 0; mi < 4; ++mi)
#pragma unroll
      for (int ni = 0; ni < 4; ++ni)
        acc[mi][ni] = MFMA_BF16(af[mi], bf[ni], acc[mi][ni], 0, 0, 0);
    __syncthreads();
  }
  // epilogue: t uniform per block (128 | 768)
  const int t_sel = n0 / 768;
  const float* bias = (t_sel == 0) ? bq : (t_sel == 1) ? bk : bv;
  unsigned short* dst = (t_sel == 0) ? Qp : (t_sel == 1) ? Kp : Vp;
#pragma unroll
  for (int ni = 0; ni < 4; ++ni) {
    const int mcol = n0 + wn * 64 + ni * 16 + l15;
    const int nw2 = mcol - t_sel * 768;
    const float bvv = bias[nw2];
    const int h = nw2 >> 6, dh = nw2 & 63;
#pragma unroll
    for (int mi = 0; mi < 4; ++mi) {
#pragma unroll
      for (int r = 0; r < 4; ++r) {
        const int token = m0 + wm * 64 + mi * 16 + (g << 2) + r;
        const int b = token >> 10, s = token & 1023;
        const long idx = ((((long)(b * 12 + h)) << 10) + s) * 64 + dh;
        dst[idx] = f2bf(acc[mi][ni][r] + bvv);
      }
    }
  }
}

// ---------------------------------------------------------------------------
// k_vt: V [B,H,S,64] -> V^T [B,H,64,S], 64x64 tiles through LDS,
// 16B-slot swizzle slot = sl ^ ((row>>3)&7) -> conflict-free read phase.
// ---------------------------------------------------------------------------
__global__ __launch_bounds__(256) void k_vt(const unsigned short* __restrict__ Vp,
                                            unsigned short* __restrict__ Vt) {
  __shared__ __align__(16) unsigned short t[64][64];
  const int bh = blockIdx.y, s0 = blockIdx.x * 64;
  const int tid = threadIdx.x;
#pragma unroll
  for (int it = 0; it < 2; ++it) {
    const int c = it * 256 + tid;
    const int row = c >> 3, sl = c & 7;
    const int slot = sl ^ ((row >> 3) & 7);
    s16x8 v = *(const s16x8*)(Vp + (((long)bh << 10) + s0 + row) * 64 + sl * 8);
    *(s16x8*)&t[row][slot * 8] = v;
  }
  __syncthreads();
#pragma unroll
  for (int it = 0; it < 2; ++it) {
    const int c = it * 256 + tid;
    const int d = c >> 3, ss = c & 7;
    const int cg = d >> 3;
    s16x8 vv;
#pragma unroll
    for (int i = 0; i < 8; ++i) {
      const int rr = ss * 8 + i;
      vv[i] = (short)t[rr][((cg ^ ((rr >> 3) & 7)) << 3) + (d & 7)];
    }
    *(s16x8*)(Vt + (((long)bh * 64 + d) << 10) + s0 + ss * 8) = vv;
  }
}

// ---------------------------------------------------------------------------
// k_attn: per (b,h,l-tile of 64). Flash loop over 16 r-tiles of 64.
// Static LDS 57856B:
//   Kl  +0     [64][64] bf16 (K rows j, XOR(row&7) 16B-slot swizzle)
//   Vl  +8192  [64][64] bf16 (V^T rows d, same swizzle)
//   FP  +16384 [64][64] bf16 (flow rows l, then P; same swizzle)
//   Dl  +24576 [2][64][64] bf16 rolling dist window (swizzled per half)
//   QDs +40960 [64][66] bf16 sheared: QDs[ib][u-ib]
//   KDs +49408 [64][66] bf16 sheared: KDs[j][u+j-63]
// scores = (QK + QDs[ib][63-j] + KDs[j][ib]) * 0.125 + flow.
// ---------------------------------------------------------------------------
__global__ __launch_bounds__(256) void k_attn(
    const unsigned short* __restrict__ Qp, const unsigned short* __restrict__ Kp,
    const unsigned short* __restrict__ Vtp, const unsigned short* __restrict__ Db,
    const unsigned short* __restrict__ Flp, float* __restrict__ Out) {
  __shared__ __align__(16) char sm[57856];
  char* Kl = sm;
  char* Vl = sm + 8192;
  char* FP = sm + 16384;
  char* Dl = sm + 24576;
  unsigned short* QDs = (unsigned short*)(sm + 40960);
  unsigned short* KDs = (unsigned short*)(sm + 49408);

  const int tid = threadIdx.x, w = tid >> 6, lane = tid & 63;
  const int g = lane >> 4, l15 = lane & 15;
  const int l0 = blockIdx.x << 6, h = blockIdx.y, b = blockIdx.z;
  const int bh = b * 12 + h;
  const unsigned short* Qb = Qp + ((long)bh << 16);
  const unsigned short* Kb = Kp + ((long)bh << 16);
  const unsigned short* Vb = Vtp + ((long)bh << 16);
  const unsigned short* Fb = Flp + ((long)b << 20);

  const int qrow = l0 + (w << 4) + l15;
  const s16x8 qf0 = *(const s16x8*)(Qb + (long)qrow * 64 + g * 8);
  const s16x8 qf1 = *(const s16x8*)(Qb + (long)qrow * 64 + 32 + g * 8);

  f32x4 oacc[4] = {};
  float mrow[4] = {-1e30f, -1e30f, -1e30f, -1e30f};
  float lrow[4] = {0.f, 0.f, 0.f, 0.f};

  for (int rt = 0; rt < 16; ++rt) {
    const int r0 = rt << 6;
    const int t0 = l0 - r0 + 960;  // window [t0, t0+127], t0 % 64 == 0

    // ---- stage K / V^T / flow (+ D halves), pre-swizzled sources ----
#pragma unroll
    for (int it = 0; it < 2; ++it) {
      const int c = (w << 7) + (it << 6) + lane;
      const int row = c >> 3, sl = c & 7;
      const int so = ((sl ^ (row & 7)) << 3);
      char* dst = sm + ((w << 7) + (it << 6)) * 16;
      gl_lds16(Kb + (long)(r0 + row) * 64 + so, dst);                  // K
      gl_lds16(Vb + (long)row * 1024 + r0 + so, dst + 8192);           // V^T
      gl_lds16(Fb + (long)(l0 + row) * 1024 + r0 + so, dst + 16384);   // flow
    }
    {
      const int nh = (rt == 0) ? 2 : 1;
      for (int hh = 0; hh < nh; ++hh) {
        const int ts = t0 + (hh << 6);
        char* dhalf = Dl + (((ts >> 6) & 1) << 13);
#pragma unroll
        for (int it = 0; it < 2; ++it) {
          const int c = (w << 7) + (it << 6) + lane;
          const int row = c >> 3, sl = c & 7;
          gl_lds16(Db + (long)(ts + row) * 64 + ((sl ^ (row & 7)) << 3),
                   dhalf + ((w << 7) + (it << 6)) * 16);
        }
      }
    }
    __syncthreads();

    // ---- pe panels -> sheared LDS stores ----
    {
      const int krow = (w << 4) + l15;
      const s16x8 kf0 = *(const s16x8*)(Kl + krow * 128 + ((g ^ (krow & 7)) << 4));
      const s16x8 kf1 = *(const s16x8*)(Kl + krow * 128 + (((4 + g) ^ (krow & 7)) << 4));
#pragma unroll
      for (int n = 0; n < 8; ++n) {
        const int pb = ((((t0 >> 6) + (n >> 2)) & 1) << 6) + ((n & 3) << 4);
        const int trow = pb + l15;
        const s16x8 d0 = *(const s16x8*)(Dl + trow * 128 + ((g ^ (trow & 7)) << 4));
        const s16x8 d1 = *(const s16x8*)(Dl + trow * 128 + (((4 + g) ^ (trow & 7)) << 4));
        f32x4 qa = {}, ka = {};
        qa = MFMA_BF16(qf0, d0, qa, 0, 0, 0);
        ka = MFMA_BF16(kf0, d0, ka, 0, 0, 0);
        qa = MFMA_BF16(qf1, d1, qa, 0, 0, 0);
        ka = MFMA_BF16(kf1, d1, ka, 0, 0, 0);
#pragma unroll
        for (int r = 0; r < 4; ++r) {
          const int prow = (w << 4) + (g << 2) + r;
          const int u = (n << 4) + l15;
          const int cq = u - prow;
          const int ck = u + prow - 63;
          if ((unsigned)cq < 64u) QDs[prow * 66 + cq] = f2bf(qa[r]);
          if ((unsigned)ck < 64u) KDs[prow * 66 + ck] = f2bf(ka[r]);
        }
      }
    }
    __syncthreads();

    // ---- scores: QK^T then shear-add panels + flow ----
    f32x4 sacc[4] = {};
#pragma unroll
    for (int n = 0; n < 4; ++n) {
      const int kr = (n << 4) + l15;
      const s16x8 b0 = *(const s16x8*)(Kl + kr * 128 + ((g ^ (kr & 7)) << 4));
      const s16x8 b1 = *(const s16x8*)(Kl + kr * 128 + (((4 + g) ^ (kr & 7)) << 4));
      sacc[n] = MFMA_BF16(qf0, b0, sacc[n], 0, 0, 0);
      sacc[n] = MFMA_BF16(qf1, b1, sacc[n], 0, 0, 0);
    }
#pragma unroll
    for (int n = 0; n < 4; ++n) {
#pragma unroll
      for (int r = 0; r < 4; ++r) {
        const int ib = (w << 4) + (g << 2) + r;  // block-local l row
        const int j = (n << 4) + l15;            // block-local r col
        const float qd = bf2f(QDs[ib * 66 + (63 - j)]);
        const float kd = bf2f(KDs[j * 66 + ib]);
        const float fv = bf2f(*(const unsigned short*)(
            FP + ib * 128 + (((j >> 3) ^ (ib & 7)) << 4) + ((j & 7) << 1)));
        sacc[n][r] = (sacc[n][r] + qd + kd) * 0.125f + fv;
      }
    }

    // ---- online softmax (rows spread over 16-lane groups) ----
    float nm[4], scl[4];
#pragma unroll
    for (int r = 0; r < 4; ++r) {
      float mx = fmaxf(fmaxf(sacc[0][r], sacc[1][r]), fmaxf(sacc[2][r], sacc[3][r]));
#pragma unroll
      for (int dd = 1; dd < 16; dd <<= 1) mx = fmaxf(mx, __shfl_xor(mx, dd, 64));
      nm[r] = fmaxf(mrow[r], mx);
      scl[r] = __expf(mrow[r] - nm[r]);
      mrow[r] = nm[r];
    }
#pragma unroll
    for (int r = 0; r < 4; ++r) {
      float p0 = __expf(sacc[0][r] - nm[r]);
      float p1 = __expf(sacc[1][r] - nm[r]);
      float p2 = __expf(sacc[2][r] - nm[r]);
      float p3 = __expf(sacc[3][r] - nm[r]);
      sacc[0][r] = p0; sacc[1][r] = p1; sacc[2][r] = p2; sacc[3][r] = p3;
      float s4 = (p0 + p1) + (p2 + p3);
#pragma unroll
      for (int dd = 1; dd < 16; dd <<= 1) s4 += __shfl_xor(s4, dd, 64);
      lrow[r] = lrow[r] * scl[r] + s4;
    }
#pragma unroll
    for (int n = 0; n < 4; ++n)
#pragma unroll
      for (int r = 0; r < 4; ++r) oacc[n][r] *= scl[r];

    // ---- write P (bf16, same swizzled layout as flow; own (ib,j) slots) ----
#pragma unroll
    for (int n = 0; n < 4; ++n) {
#pragma unroll
      for (int r = 0; r < 4; ++r) {
        const int ib = (w << 4) + (g << 2) + r;
        const int j = (n << 4) + l15;
        *(unsigned short*)(FP + ib * 128 + (((j >> 3) ^ (ib & 7)) << 4) +
                           ((j & 7) << 1)) = f2bf(sacc[n][r]);
      }
    }

    // ---- PV (P rows are wave-local: no extra barrier needed) ----
#pragma unroll
    for (int k0 = 0; k0 < 2; ++k0) {
      const int prow = (w << 4) + l15;
      const s16x8 pf = *(const s16x8*)(
          FP + prow * 128 + ((((k0 << 2) + g) ^ (prow & 7)) << 4));
#pragma unroll
      for (int n = 0; n < 4; ++n) {
        const int vrow = (n << 4) + l15;
        const s16x8 vf = *(const s16x8*)(
            Vl + vrow * 128 + ((((k0 << 2) + g) ^ (vrow & 7)) << 4));
        oacc[n] = MFMA_BF16(pf, vf, oacc[n], 0, 0, 0);
      }
    }
    __syncthreads();
  }

  // ---- epilogue: out[b, l, h*64+d] fp32 ----
#pragma unroll
  for (int n = 0; n < 4; ++n) {
#pragma unroll
    for (int r = 0; r < 4; ++r) {
      const int l = l0 + (w << 4) + (g << 2) + r;
      const int d = (n << 4) + l15;
      Out[((long)(b * 1024 + l)) * 768 + h * 64 + d] = oacc[n][r] / lrow[r];
    }
  }
}

// ---------------------------------------------------------------------------
extern "C" void kernel_launch(void* const* d_in, const int* in_sizes, int n_in,
                              void* d_out, int out_size, void* d_ws, size_t ws_size,
                              hipStream_t stream) {
  const float* hs = (const float*)d_in[0];
  const float* Wq = (const float*)d_in[1];
  const float* bq = (const float*)d_in[2];
  const float* Wk = (const float*)d_in[3];
  const float* bk = (const float*)d_in[4];
  const float* Wv = (const float*)d_in[5];
  const float* bv = (const float*)d_in[6];
  const float* de = (const float*)d_in[7];
  const float* ce = (const float*)d_in[8];
  const float* dfe = (const float*)d_in[9];
  const float* rfe = (const float*)d_in[10];
  const int* cm = (const int*)d_in[11];
  const int* dm = (const int*)d_in[12];
  const int* rm = (const int*)d_in[13];
  float* out = (float*)d_out;
  char* ws = (char*)d_ws;

  // workspace layout (bytes), total 43,646,976
  unsigned short* hsb = (unsigned short*)(ws + 0);         // 6291456
  unsigned short* wb  = (unsigned short*)(ws + 6291456);   // 3538944
  unsigned short* db  = (unsigned short*)(ws + 9830400);   // 262144
  unsigned short* fl  = (unsigned short*)(ws + 10092544);  // 8388608
  unsigned short* qp  = (unsigned short*)(ws + 18481152);  // 6291456
  unsigned short* kp  = (unsigned short*)(ws + 24772608);  // 6291456
  unsigned short* vp  = (unsigned short*)(ws + 31064064);  // 6291456
  unsigned short* vt  = (unsigned short*)(ws + 37355520);  // 6291456

  k_prep<<<4928, 256, 0, stream>>>(hs, Wq, Wk, Wv, de, hsb, wb, db);
  k_flow<<<4096, 256, 0, stream>>>(cm, dm, rm, ce, dfe, rfe, fl);
  k_qkv<<<dim3(18, 32), 256, 0, stream>>>(hsb, wb, bq, bk, bv, qp, kp, vp);
  k_vt<<<dim3(16, 48), 256, 0, stream>>>(vp, vt);
  k_attn<<<dim3(16, 12, 4), 256, 0, stream>>>(qp, kp, vt, db, fl, out);
}

// Round 3
// 151.113 us; speedup vs baseline: 1.3005x; 1.3005x over previous
//
#include <hip/hip_runtime.h>

// ---------------------------------------------------------------------------
// WelkirSelfAttention: B=4 S=1024 D=768 H=12 DH=64, relative_key_query bias +
// flow-type scalar bias. Pipeline:
//   k_prep : cast hidden/W{q,k,v}/dist_emb -> bf16 (dist padded to 2048 rows)
//   k_flow : flow[b,i,j] = ce[cfg]+de[dfg]+re[rdg] (idx0 -> 0) -> bf16 [B,S,S]
//   k_qkv  : GEMM [4096 x 2304 x 768] bf16 MFMA -> Q,K,V bf16 [B,H,S,64]
//   k_vt   : V -> V^T  [B,H,64,S]
//   k_attn : fused flash attention, banded QD/KD panels, 50688B LDS
//            (3 blocks/CU; grid 768 = 3*256 -> all co-resident, no tail)
// ---------------------------------------------------------------------------

typedef __attribute__((ext_vector_type(4))) float f32x4;
typedef __attribute__((ext_vector_type(8))) short s16x8;

#define MFMA_BF16 __builtin_amdgcn_mfma_f32_16x16x32_bf16

__device__ __forceinline__ unsigned short f2bf(float x) {
  unsigned u = __builtin_bit_cast(unsigned, x);
  u += 0x7fffu + ((u >> 16) & 1u);
  return (unsigned short)(u >> 16);
}
__device__ __forceinline__ float bf2f(unsigned short h) {
  unsigned u = ((unsigned)h) << 16;
  return __builtin_bit_cast(float, u);
}
__device__ __forceinline__ void gl_lds16(const void* g, void* l) {
  __builtin_amdgcn_global_load_lds(
      (const __attribute__((address_space(1))) unsigned int*)g,
      (__attribute__((address_space(3))) unsigned int*)l, 16, 0, 0);
}

// ---------------------------------------------------------------------------
// k_prep: bf16 casts. ranges: [0,3145728) hs ; [.,+1769472) packed W ; dist.
// ---------------------------------------------------------------------------
__global__ __launch_bounds__(256) void k_prep(
    const float* __restrict__ hs, const float* __restrict__ wq,
    const float* __restrict__ wk, const float* __restrict__ wv,
    const float* __restrict__ de, unsigned short* __restrict__ hsb,
    unsigned short* __restrict__ wb, unsigned short* __restrict__ db) {
  const long HSN = 3145728, WN = 1769472;
  long e = ((long)blockIdx.x * 256 + threadIdx.x) * 4;
  if (e < HSN) {
    float4 v = *(const float4*)(hs + e);
    *(ushort4*)(hsb + e) = make_ushort4(f2bf(v.x), f2bf(v.y), f2bf(v.z), f2bf(v.w));
  } else if (e < HSN + WN) {
    long ew = e - HSN;
    const float* src = (ew >= 1179648) ? wv : ((ew >= 589824) ? wk : wq);
    long off = (ew >= 1179648) ? (ew - 1179648) : ((ew >= 589824) ? (ew - 589824) : ew);
    float4 v = *(const float4*)(src + off);
    *(ushort4*)(wb + ew) = make_ushort4(f2bf(v.x), f2bf(v.y), f2bf(v.z), f2bf(v.w));
  } else {
    long ed = e - HSN - WN;  // [0, 131072)
    ushort4 ov;
    if (ed < 131008) {  // 2047*64 valid rows, rest zero pad
      float4 v = *(const float4*)(de + ed);
      ov = make_ushort4(f2bf(v.x), f2bf(v.y), f2bf(v.z), f2bf(v.w));
    } else {
      ov = make_ushort4(0, 0, 0, 0);
    }
    *(ushort4*)(db + ed) = ov;
  }
}

// ---------------------------------------------------------------------------
// k_flow: combined scalar flow bias, row 0 of each embedding forced to zero.
// ---------------------------------------------------------------------------
__global__ __launch_bounds__(256) void k_flow(
    const int* __restrict__ cm, const int* __restrict__ dm,
    const int* __restrict__ rm, const float* __restrict__ ce,
    const float* __restrict__ dfe, const float* __restrict__ rfe,
    unsigned short* __restrict__ fl) {
  long e = ((long)blockIdx.x * 256 + threadIdx.x) * 4;
  int4 c = *(const int4*)(cm + e);
  int4 d = *(const int4*)(dm + e);
  int4 r = *(const int4*)(rm + e);
  ushort4 ov;
  ov.x = f2bf((c.x ? ce[c.x] : 0.f) + (d.x ? dfe[d.x] : 0.f) + (r.x ? rfe[r.x] : 0.f));
  ov.y = f2bf((c.y ? ce[c.y] : 0.f) + (d.y ? dfe[d.y] : 0.f) + (r.y ? rfe[r.y] : 0.f));
  ov.z = f2bf((c.z ? ce[c.z] : 0.f) + (d.z ? dfe[d.z] : 0.f) + (r.z ? rfe[r.z] : 0.f));
  ov.w = f2bf((c.w ? ce[c.w] : 0.f) + (d.w ? dfe[d.w] : 0.f) + (r.w ? rfe[r.w] : 0.f));
  *(ushort4*)(fl + e) = ov;
}

// ---------------------------------------------------------------------------
// k_qkv: C[token,m] = hs_bf16 @ W'[m,:]^T + bias; scatter to [t][B,H,S,64] bf16
// 128x128 tile, BK=32, 4 waves, global_load_lds w16, XOR((row>>1)&3) swizzle.
// ---------------------------------------------------------------------------
__global__ __launch_bounds__(256) void k_qkv(
    const unsigned short* __restrict__ A, const unsigned short* __restrict__ W,
    const float* __restrict__ bq, const float* __restrict__ bk,
    const float* __restrict__ bv, unsigned short* __restrict__ Qp,
    unsigned short* __restrict__ Kp, unsigned short* __restrict__ Vp) {
  __shared__ __align__(16) char smq[16384];
  char* sa = smq;
  char* sb = smq + 8192;
  const int tid = threadIdx.x, w = tid >> 6, lane = tid & 63;
  const int g = lane >> 4, l15 = lane & 15;
  const int n0 = blockIdx.x * 128, m0 = blockIdx.y * 128;
  const int wm = w >> 1, wn = w & 1;
  f32x4 acc[4][4] = {};
  for (int k0 = 0; k0 < 768; k0 += 32) {
#pragma unroll
    for (int it = 0; it < 2; ++it) {
      const int c = (w << 7) + (it << 6) + lane;
      const int row = c >> 2, sl = c & 3;
      const int so = ((sl ^ ((row >> 1) & 3)) << 3);
      char* dst = smq + ((w << 7) + (it << 6)) * 16;
      gl_lds16(A + (long)(m0 + row) * 768 + k0 + so, dst);
      gl_lds16(W + (long)(n0 + row) * 768 + k0 + so, dst + 8192);
    }
    __syncthreads();
    s16x8 af[4], bf[4];
#pragma unroll
    for (int mi = 0; mi < 4; ++mi) {
      const int row = wm * 64 + mi * 16 + l15;
      af[mi] = *(const s16x8*)(sa + row * 64 + ((g ^ ((row >> 1) & 3)) << 4));
    }
#pragma unroll
    for (int ni = 0; ni < 4; ++ni) {
      const int row = wn * 64 + ni * 16 + l15;
      bf[ni] = *(const s16x8*)(sb + row * 64 + ((g ^ ((row >> 1) & 3)) << 4));
    }
#pragma unroll
    for (int mi = 0; mi < 4; ++mi)
#pragma unroll
      for (int ni = 0; ni < 4; ++ni)
        acc[mi][ni] = MFMA_BF16(af[mi], bf[ni], acc[mi][ni], 0, 0, 0);
    __syncthreads();
  }
  const int t_sel = n0 / 768;
  const float* bias = (t_sel == 0) ? bq : (t_sel == 1) ? bk : bv;
  unsigned short* dst = (t_sel == 0) ? Qp : (t_sel == 1) ? Kp : Vp;
#pragma unroll
  for (int ni = 0; ni < 4; ++ni) {
    const int mcol = n0 + wn * 64 + ni * 16 + l15;
    const int nw2 = mcol - t_sel * 768;
    const float bvv = bias[nw2];
    const int h = nw2 >> 6, dh = nw2 & 63;
#pragma unroll
    for (int mi = 0; mi < 4; ++mi) {
#pragma unroll
      for (int r = 0; r < 4; ++r) {
        const int token = m0 + wm * 64 + mi * 16 + (g << 2) + r;
        const int b = token >> 10, s = token & 1023;
        const long idx = ((((long)(b * 12 + h)) << 10) + s) * 64 + dh;
        dst[idx] = f2bf(acc[mi][ni][r] + bvv);
      }
    }
  }
}

// ---------------------------------------------------------------------------
// k_vt: V [B,H,S,64] -> V^T [B,H,64,S], 64x64 tiles through LDS.
// ---------------------------------------------------------------------------
__global__ __launch_bounds__(256) void k_vt(const unsigned short* __restrict__ Vp,
                                            unsigned short* __restrict__ Vt) {
  __shared__ __align__(16) unsigned short t[64][64];
  const int bh = blockIdx.y, s0 = blockIdx.x * 64;
  const int tid = threadIdx.x;
#pragma unroll
  for (int it = 0; it < 2; ++it) {
    const int c = it * 256 + tid;
    const int row = c >> 3, sl = c & 7;
    const int slot = sl ^ ((row >> 3) & 7);
    s16x8 v = *(const s16x8*)(Vp + (((long)bh << 10) + s0 + row) * 64 + sl * 8);
    *(s16x8*)&t[row][slot * 8] = v;
  }
  __syncthreads();
#pragma unroll
  for (int it = 0; it < 2; ++it) {
    const int c = it * 256 + tid;
    const int d = c >> 3, ss = c & 7;
    const int cg = d >> 3;
    s16x8 vv;
#pragma unroll
    for (int i = 0; i < 8; ++i) {
      const int rr = ss * 8 + i;
      vv[i] = (short)t[rr][((cg ^ ((rr >> 3) & 7)) << 3) + (d & 7)];
    }
    *(s16x8*)(Vt + (((long)bh * 64 + d) << 10) + s0 + ss * 8) = vv;
  }
}

// ---------------------------------------------------------------------------
// k_attn: per (b,h,l-tile of 64). Flash loop over 16 r-tiles of 64.
// Static LDS 50688B (3 blocks/CU):
//   Kl  +0     [64][64] bf16, XOR(row&7) 16B-slot swizzle
//   Vl  +8192  [64][64] bf16 (V^T rows d), same swizzle
//   Dl  +16384 [2][64][64] bf16 rolling dist window, same swizzle per half
//   QDs +32768 stride 72 shorts (144B rows): sheared QDs[ib][u-ib];
//              P overlays this region after QD consumption (wave-local rows)
//   KDs +41984 stride 68 shorts (136B rows): sheared KDs[j][u+j-63]
// Flow tile is prefetched into 16 registers/lane (L2-hot, no LDS).
// Banded panels: QD tiles n in [w,w+4], KD tiles n in [3-w,7-w] (20 MFMA).
// scores = (QK + QDs[ib][63-j] + KDs[j][ib]) * 0.125 + flow.
// ---------------------------------------------------------------------------
__global__ __launch_bounds__(256) void k_attn(
    const unsigned short* __restrict__ Qp, const unsigned short* __restrict__ Kp,
    const unsigned short* __restrict__ Vtp, const unsigned short* __restrict__ Db,
    const unsigned short* __restrict__ Flp, float* __restrict__ Out) {
  __shared__ __align__(16) char sm[50688];
  char* Kl = sm;
  char* Vl = sm + 8192;
  char* Dl = sm + 16384;
  unsigned short* QDs = (unsigned short*)(sm + 32768);  // stride 72
  char* Pl = sm + 32768;                                // stride 144B
  unsigned short* KDs = (unsigned short*)(sm + 41984);  // stride 68

  const int tid = threadIdx.x, w = tid >> 6, lane = tid & 63;
  const int g = lane >> 4, l15 = lane & 15;
  const int l0 = blockIdx.x << 6, h = blockIdx.y, b = blockIdx.z;
  const int bh = b * 12 + h;
  const unsigned short* Qb = Qp + ((long)bh << 16);
  const unsigned short* Kb = Kp + ((long)bh << 16);
  const unsigned short* Vb = Vtp + ((long)bh << 16);
  const unsigned short* Fb = Flp + ((long)b << 20);

  const int qrow = l0 + (w << 4) + l15;
  const s16x8 qf0 = *(const s16x8*)(Qb + (long)qrow * 64 + g * 8);
  const s16x8 qf1 = *(const s16x8*)(Qb + (long)qrow * 64 + 32 + g * 8);

  f32x4 oacc[4] = {};
  float mrow[4] = {-1e30f, -1e30f, -1e30f, -1e30f};
  float lrow[4] = {0.f, 0.f, 0.f, 0.f};

  for (int rt = 0; rt < 16; ++rt) {
    const int r0 = rt << 6;
    const int t0 = l0 - r0 + 960;  // window [t0, t0+127], t0 % 64 == 0

    // ---- prefetch flow tile into registers (consumed in score phase) ----
    unsigned short fvr[16];
#pragma unroll
    for (int n = 0; n < 4; ++n)
#pragma unroll
      for (int r = 0; r < 4; ++r)
        fvr[n * 4 + r] = Fb[(long)(l0 + (w << 4) + (g << 2) + r) * 1024 +
                            r0 + (n << 4) + l15];

    // ---- stage K / V^T (+ D half), pre-swizzled sources ----
#pragma unroll
    for (int it = 0; it < 2; ++it) {
      const int c = (w << 7) + (it << 6) + lane;
      const int row = c >> 3, sl = c & 7;
      const int so = ((sl ^ (row & 7)) << 3);
      char* dst = sm + ((w << 7) + (it << 6)) * 16;
      gl_lds16(Kb + (long)(r0 + row) * 64 + so, dst);            // K
      gl_lds16(Vb + (long)row * 1024 + r0 + so, dst + 8192);     // V^T
    }
    {
      const int nh = (rt == 0) ? 2 : 1;
      for (int hh = 0; hh < nh; ++hh) {
        const int ts = t0 + (hh << 6);
        char* dhalf = Dl + (((ts >> 6) & 1) << 13);
#pragma unroll
        for (int it = 0; it < 2; ++it) {
          const int c = (w << 7) + (it << 6) + lane;
          const int row = c >> 3, sl = c & 7;
          gl_lds16(Db + (long)(ts + row) * 64 + ((sl ^ (row & 7)) << 3),
                   dhalf + ((w << 7) + (it << 6)) * 16);
        }
      }
    }
    __syncthreads();

    // ---- banded pe panels -> sheared LDS stores ----
    {
      const int krow = (w << 4) + l15;
      const s16x8 kf0 = *(const s16x8*)(Kl + krow * 128 + ((g ^ (krow & 7)) << 4));
      const s16x8 kf1 = *(const s16x8*)(Kl + krow * 128 + (((4 + g) ^ (krow & 7)) << 4));
#pragma unroll
      for (int n = 0; n < 8; ++n) {
        const bool doQ = (n >= w) && (n <= w + 4);
        const bool doK = (n >= 3 - w) && (n <= 7 - w);
        if (!(doQ || doK)) continue;
        const int pb = ((((t0 >> 6) + (n >> 2)) & 1) << 6) + ((n & 3) << 4);
        const int trow = pb + l15;
        const s16x8 d0 = *(const s16x8*)(Dl + trow * 128 + ((g ^ (trow & 7)) << 4));
        const s16x8 d1 = *(const s16x8*)(Dl + trow * 128 + (((4 + g) ^ (trow & 7)) << 4));
        f32x4 qa = {}, ka = {};
        if (doQ) {
          qa = MFMA_BF16(qf0, d0, qa, 0, 0, 0);
          qa = MFMA_BF16(qf1, d1, qa, 0, 0, 0);
        }
        if (doK) {
          ka = MFMA_BF16(kf0, d0, ka, 0, 0, 0);
          ka = MFMA_BF16(kf1, d1, ka, 0, 0, 0);
        }
#pragma unroll
        for (int r = 0; r < 4; ++r) {
          const int prow = (w << 4) + (g << 2) + r;
          const int u = (n << 4) + l15;
          if (doQ) {
            const int cq = u - prow;
            if ((unsigned)cq < 64u) QDs[prow * 72 + cq] = f2bf(qa[r]);
          }
          if (doK) {
            const int ck = u + prow - 63;
            if ((unsigned)ck < 64u) KDs[prow * 68 + ck] = f2bf(ka[r]);
          }
        }
      }
    }
    __syncthreads();

    // ---- scores: QK^T then shear-add panels + flow regs ----
    f32x4 sacc[4] = {};
#pragma unroll
    for (int n = 0; n < 4; ++n) {
      const int kr = (n << 4) + l15;
      const s16x8 b0 = *(const s16x8*)(Kl + kr * 128 + ((g ^ (kr & 7)) << 4));
      const s16x8 b1 = *(const s16x8*)(Kl + kr * 128 + (((4 + g) ^ (kr & 7)) << 4));
      sacc[n] = MFMA_BF16(qf0, b0, sacc[n], 0, 0, 0);
      sacc[n] = MFMA_BF16(qf1, b1, sacc[n], 0, 0, 0);
    }
#pragma unroll
    for (int n = 0; n < 4; ++n) {
#pragma unroll
      for (int r = 0; r < 4; ++r) {
        const int ib = (w << 4) + (g << 2) + r;  // block-local l row
        const int j = (n << 4) + l15;            // block-local r col
        const float qd = bf2f(QDs[ib * 72 + (63 - j)]);
        const float kd = bf2f(KDs[j * 68 + ib]);
        sacc[n][r] = (sacc[n][r] + qd + kd) * 0.125f + bf2f(fvr[n * 4 + r]);
      }
    }

    // ---- online softmax (rows spread over 16-lane groups) ----
    float nm[4], scl[4];
#pragma unroll
    for (int r = 0; r < 4; ++r) {
      float mx = fmaxf(fmaxf(sacc[0][r], sacc[1][r]), fmaxf(sacc[2][r], sacc[3][r]));
#pragma unroll
      for (int dd = 1; dd < 16; dd <<= 1) mx = fmaxf(mx, __shfl_xor(mx, dd, 64));
      nm[r] = fmaxf(mrow[r], mx);
      scl[r] = __expf(mrow[r] - nm[r]);
      mrow[r] = nm[r];
    }
#pragma unroll
    for (int r = 0; r < 4; ++r) {
      float p0 = __expf(sacc[0][r] - nm[r]);
      float p1 = __expf(sacc[1][r] - nm[r]);
      float p2 = __expf(sacc[2][r] - nm[r]);
      float p3 = __expf(sacc[3][r] - nm[r]);
      sacc[0][r] = p0; sacc[1][r] = p1; sacc[2][r] = p2; sacc[3][r] = p3;
      float s4 = (p0 + p1) + (p2 + p3);
#pragma unroll
      for (int dd = 1; dd < 16; dd <<= 1) s4 += __shfl_xor(s4, dd, 64);
      lrow[r] = lrow[r] * scl[r] + s4;
    }
#pragma unroll
    for (int n = 0; n < 4; ++n)
#pragma unroll
      for (int r = 0; r < 4; ++r) oacc[n][r] *= scl[r];

    // ---- write P over QDs region (wave-local rows; no barrier needed) ----
#pragma unroll
    for (int n = 0; n < 4; ++n) {
#pragma unroll
      for (int r = 0; r < 4; ++r) {
        const int ib = (w << 4) + (g << 2) + r;
        const int j = (n << 4) + l15;
        *(unsigned short*)(Pl + ib * 144 + (((j >> 3) ^ (ib & 7)) << 4) +
                           ((j & 7) << 1)) = f2bf(sacc[n][r]);
      }
    }

    // ---- PV ----
#pragma unroll
    for (int k0 = 0; k0 < 2; ++k0) {
      const int prow = (w << 4) + l15;
      const s16x8 pf = *(const s16x8*)(
          Pl + prow * 144 + ((((k0 << 2) + g) ^ (prow & 7)) << 4));
#pragma unroll
      for (int n = 0; n < 4; ++n) {
        const int vrow = (n << 4) + l15;
        const s16x8 vf = *(const s16x8*)(
            Vl + vrow * 128 + ((((k0 << 2) + g) ^ (vrow & 7)) << 4));
        oacc[n] = MFMA_BF16(pf, vf, oacc[n], 0, 0, 0);
      }
    }
    __syncthreads();
  }

  // ---- epilogue: out[b, l, h*64+d] fp32 ----
#pragma unroll
  for (int n = 0; n < 4; ++n) {
#pragma unroll
    for (int r = 0; r < 4; ++r) {
      const int l = l0 + (w << 4) + (g << 2) + r;
      const int d = (n << 4) + l15;
      Out[((long)(b * 1024 + l)) * 768 + h * 64 + d] = oacc[n][r] / lrow[r];
    }
  }
}

// ---------------------------------------------------------------------------
extern "C" void kernel_launch(void* const* d_in, const int* in_sizes, int n_in,
                              void* d_out, int out_size, void* d_ws, size_t ws_size,
                              hipStream_t stream) {
  const float* hs = (const float*)d_in[0];
  const float* Wq = (const float*)d_in[1];
  const float* bq = (const float*)d_in[2];
  const float* Wk = (const float*)d_in[3];
  const float* bk = (const float*)d_in[4];
  const float* Wv = (const float*)d_in[5];
  const float* bv = (const float*)d_in[6];
  const float* de = (const float*)d_in[7];
  const float* ce = (const float*)d_in[8];
  const float* dfe = (const float*)d_in[9];
  const float* rfe = (const float*)d_in[10];
  const int* cm = (const int*)d_in[11];
  const int* dm = (const int*)d_in[12];
  const int* rm = (const int*)d_in[13];
  float* out = (float*)d_out;
  char* ws = (char*)d_ws;

  unsigned short* hsb = (unsigned short*)(ws + 0);         // 6291456
  unsigned short* wb  = (unsigned short*)(ws + 6291456);   // 3538944
  unsigned short* db  = (unsigned short*)(ws + 9830400);   // 262144
  unsigned short* fl  = (unsigned short*)(ws + 10092544);  // 8388608
  unsigned short* qp  = (unsigned short*)(ws + 18481152);  // 6291456
  unsigned short* kp  = (unsigned short*)(ws + 24772608);  // 6291456
  unsigned short* vp  = (unsigned short*)(ws + 31064064);  // 6291456
  unsigned short* vt  = (unsigned short*)(ws + 37355520);  // 6291456

  k_prep<<<4928, 256, 0, stream>>>(hs, Wq, Wk, Wv, de, hsb, wb, db);
  k_flow<<<4096, 256, 0, stream>>>(cm, dm, rm, ce, dfe, rfe, fl);
  k_qkv<<<dim3(18, 32), 256, 0, stream>>>(hsb, wb, bq, bk, bv, qp, kp, vp);
  k_vt<<<dim3(16, 48), 256, 0, stream>>>(vp, vt);
  k_attn<<<dim3(16, 12, 4), 256, 0, stream>>>(qp, kp, vt, db, fl, out);
}